// Round 1
// baseline (948.072 us; speedup 1.0000x reference)
//
#include <hip/hip_runtime.h>
#include <math.h>

// ============================================================================
// StableHolographicLayer — fused MI355X kernel.
//
// Math: for mod i in 0..7:  h = x + fv[i] + (i? 0.1/i * S : 0)
//       h = LN1(h); g = GELU(h@w1+b1); o = g@w2+b2; state = LN2(o); S += state
// out = LN(S/8) @ comb_w + comb_b
//
// Precision: all GEMMs via split-bf16 (hi+lo) MFMA 16x16x32, 3 products
// (hi*hi + lo*hi + hi*lo), fp32 accumulate -> ~2^-17 relative error.
//
// Layouts:
//  - block = 64 batch rows, 256 threads (4 waves). x, S in registers
//    (thread t: row t>>2, cols (t&3)*32..+32).
//  - LDS 64 KB: A planes (LN out, bf16 hi/lo, [64][128], 16KB each),
//    H planes (GELU out for one 128-col half, 16KB each). A region is
//    reused as f32 [64][128] GEMM2-output buffer for LN2.
//    All tiles swizzled: byte ^= ((row&7)<<4)  (uniform 8 lanes / bank group).
//  - weights pre-converted (setup kernel) into fragment-ordered bf16 hi/lo:
//    one global_load_dwordx4 per lane per fragment, fully coalesced.
// MFMA maps assumed (16x16x32): A: row=l&15, k=(l>>4)*8+i ; B: col=l&15,
// same k map; D: col=l&15, row=(l>>4)*4+j (verified layout per guide).
// ============================================================================

#define NMOD 8

typedef float  f32x4  __attribute__((ext_vector_type(4)));
typedef __bf16 bf16x8 __attribute__((ext_vector_type(8)));
typedef unsigned short u16x8 __attribute__((ext_vector_type(8)));

// LDS byte offsets
#define AHI_OFF 0u
#define ALO_OFF 16384u
#define HHI_OFF 32768u
#define HLO_OFF 49152u

// workspace byte offsets
#define WS_W1 0u          // [8][2][4][16][64][8] u16 : 1 MiB
#define WS_W2 1048576u    // [8][2][8][8][64][8]  u16 : 1 MiB
#define WS_CW 2097152u    // [2][4][8][64][8]     u16 : 64 KiB
#define WS_FV 2162688u    // [8][128] f32 : 4 KiB

static __device__ __forceinline__ unsigned short f32_to_bf16_rn(float f) {
    union { float f; unsigned u; } a; a.f = f;
    unsigned u = a.u;
    u += 0x7fffu + ((u >> 16) & 1u);   // round-to-nearest-even (values are finite/benign)
    return (unsigned short)(u >> 16);
}
static __device__ __forceinline__ float bf16_to_f32(unsigned short h) {
    union { unsigned u; float f; } a; a.u = ((unsigned)h) << 16;
    return a.f;
}
static __device__ __forceinline__ float gelu_exact(float y) {
    return 0.5f * y * (1.0f + erff(y * 0.70710678118654752440f));
}

#define MFMA16(a, b, c) __builtin_amdgcn_mfma_f32_16x16x32_bf16((a), (b), (c), 0, 0, 0)

// ---------------------------------------------------------------------------
// Setup: convert w1/w2/comb_w into MFMA-fragment-ordered bf16 hi/lo planes.
// ---------------------------------------------------------------------------
__global__ void setup_weights(const float* __restrict__ w1,
                              const float* __restrict__ w2,
                              const float* __restrict__ cw,
                              unsigned short* __restrict__ w1cv,
                              unsigned short* __restrict__ w2cv,
                              unsigned short* __restrict__ cwcv)
{
    unsigned id = blockIdx.x * blockDim.x + threadIdx.x;
    if (id < 262144u) {                       // w1: [8][128][256]
        unsigned i8 = id & 7u;
        unsigned l  = (id >> 3) & 63u;
        unsigned nt = (id >> 9) & 15u;        // n-tile 0..15 (256 cols)
        unsigned ks = (id >> 13) & 3u;        // k-step 0..3  (128 k)
        unsigned mo = id >> 15;
        unsigned k = ks * 32u + ((l >> 4) << 3) + i8;
        unsigned c = nt * 16u + (l & 15u);
        float v = w1[(mo * 128u + k) * 256u + c];
        unsigned short hh = f32_to_bf16_rn(v);
        unsigned short ll = f32_to_bf16_rn(v - bf16_to_f32(hh));
        w1cv[((((mo * 2u + 0u) * 4u + ks) * 16u + nt) * 64u + l) * 8u + i8] = hh;
        w1cv[((((mo * 2u + 1u) * 4u + ks) * 16u + nt) * 64u + l) * 8u + i8] = ll;
    } else if (id < 524288u) {                // w2: [8][256][128]
        unsigned id2 = id - 262144u;
        unsigned i8 = id2 & 7u;
        unsigned l  = (id2 >> 3) & 63u;
        unsigned nt = (id2 >> 9) & 7u;        // n-tile 0..7 (128 cols)
        unsigned kt = (id2 >> 12) & 7u;       // k-step 0..7 (256 k)
        unsigned mo = id2 >> 15;
        unsigned k = kt * 32u + ((l >> 4) << 3) + i8;
        unsigned c = nt * 16u + (l & 15u);
        float v = w2[(mo * 256u + k) * 128u + c];
        unsigned short hh = f32_to_bf16_rn(v);
        unsigned short ll = f32_to_bf16_rn(v - bf16_to_f32(hh));
        w2cv[((((mo * 2u + 0u) * 8u + kt) * 8u + nt) * 64u + l) * 8u + i8] = hh;
        w2cv[((((mo * 2u + 1u) * 8u + kt) * 8u + nt) * 64u + l) * 8u + i8] = ll;
    } else if (id < 540672u) {                // comb_w: [128][128]
        unsigned id3 = id - 524288u;
        unsigned i8 = id3 & 7u;
        unsigned l  = (id3 >> 3) & 63u;
        unsigned nt = (id3 >> 9) & 7u;
        unsigned ks = id3 >> 12;              // 0..3
        unsigned k = ks * 32u + ((l >> 4) << 3) + i8;
        unsigned c = nt * 16u + (l & 15u);
        float v = cw[k * 128u + c];
        unsigned short hh = f32_to_bf16_rn(v);
        unsigned short ll = f32_to_bf16_rn(v - bf16_to_f32(hh));
        cwcv[(((0u * 4u + ks) * 8u + nt) * 64u + l) * 8u + i8] = hh;
        cwcv[(((1u * 4u + ks) * 8u + nt) * 64u + l) * 8u + i8] = ll;
    }
}

// fv[i][d] = sigmoid(pos[i] . spatial_mix[i][:,d]) * mean_k(field_basis[i][k][d])
__global__ void setup_fv(const float* __restrict__ fb,
                         const float* __restrict__ sm,
                         float* __restrict__ fv)
{
    unsigned tid = blockIdx.x * blockDim.x + threadIdx.x;   // 0..1023
    unsigned i = tid >> 7, d = tid & 127u;
    float px = (float)((i >> 2) & 1u);
    float py = (float)((i >> 1) & 1u);
    float pz = (float)(i & 1u);
    float dot = px * sm[(i * 3u + 0u) * 128u + d]
              + py * sm[(i * 3u + 1u) * 128u + d]
              + pz * sm[(i * 3u + 2u) * 128u + d];
    float pw = 1.0f / (1.0f + expf(-dot));
    float mb = 0.0f;
    #pragma unroll
    for (int k = 0; k < 8; ++k) mb += fb[(i * 8u + (unsigned)k) * 128u + d];
    mb *= 0.125f;
    fv[i * 128u + d] = pw * mb;
}

// ---------------------------------------------------------------------------
// Main fused kernel. grid = 2048 x 256, 64 rows/block, 64 KB LDS (2 blk/CU).
// ---------------------------------------------------------------------------
__global__ __launch_bounds__(256, 2)
void holo_main(const float* __restrict__ x,
               const float* __restrict__ ln1_g, const float* __restrict__ ln1_b,
               const float* __restrict__ bias1, const float* __restrict__ bias2,
               const float* __restrict__ ln2_g, const float* __restrict__ ln2_b,
               const float* __restrict__ cln_g, const float* __restrict__ cln_b,
               const float* __restrict__ comb_b,
               const unsigned short* __restrict__ w1cv,
               const unsigned short* __restrict__ w2cv,
               const unsigned short* __restrict__ cwcv,
               const float* __restrict__ fv,
               float* __restrict__ out)
{
    __shared__ __align__(16) unsigned char lds[65536];

    const unsigned t  = threadIdx.x;
    const unsigned r  = t >> 2;        // LN-phase row 0..63
    const unsigned q  = t & 3u;        // LN-phase col quarter
    const unsigned w  = t >> 6;        // wave 0..3
    const unsigned l  = t & 63u;       // lane
    const unsigned lr = l & 15u;
    const unsigned lg = l >> 4;
    const unsigned drow = lg * 4u;     // D-fragment base row
    const unsigned row0 = blockIdx.x * 64u;

    const f32x4 FZ = {0.f, 0.f, 0.f, 0.f};

    float xv[32], Sv[32];
    {
        const float4* xp = (const float4*)(x + (row0 + r) * 128u + q * 32u);
        #pragma unroll
        for (int u = 0; u < 8; ++u) {
            float4 v = xp[u];
            xv[4*u+0] = v.x; xv[4*u+1] = v.y; xv[4*u+2] = v.z; xv[4*u+3] = v.w;
        }
        #pragma unroll
        for (int j = 0; j < 32; ++j) Sv[j] = 0.f;
    }

    for (int mod = 0; mod < NMOD; ++mod) {
        // ------------- LN1(x + fv + coef*S) -> A planes (bf16 hi/lo) -------------
        {
            const float coef = (mod == 0) ? 0.0f : (0.1f / (float)mod);
            float h[32];
            const float4* fvp = (const float4*)(fv + (unsigned)mod * 128u + q * 32u);
            #pragma unroll
            for (int u = 0; u < 8; ++u) {
                float4 f4 = fvp[u];
                h[4*u+0] = xv[4*u+0] + f4.x + coef * Sv[4*u+0];
                h[4*u+1] = xv[4*u+1] + f4.y + coef * Sv[4*u+1];
                h[4*u+2] = xv[4*u+2] + f4.z + coef * Sv[4*u+2];
                h[4*u+3] = xv[4*u+3] + f4.w + coef * Sv[4*u+3];
            }
            float s = 0.f, ss = 0.f;
            #pragma unroll
            for (int j = 0; j < 32; ++j) { s += h[j]; ss += h[j] * h[j]; }
            s += __shfl_xor(s, 1); ss += __shfl_xor(ss, 1);
            s += __shfl_xor(s, 2); ss += __shfl_xor(ss, 2);
            const float mean = s * (1.0f / 128.0f);
            const float var  = ss * (1.0f / 128.0f) - mean * mean;
            const float rstd = 1.0f / sqrtf(var + 1e-5f);
            const float4* gp = (const float4*)(ln1_g + (unsigned)mod * 128u + q * 32u);
            const float4* bp = (const float4*)(ln1_b + (unsigned)mod * 128u + q * 32u);
            #pragma unroll
            for (int u2 = 0; u2 < 4; ++u2) {
                float gg[8], bbv[8];
                float4 a0 = gp[2*u2], a1 = gp[2*u2+1];
                float4 c0 = bp[2*u2], c1 = bp[2*u2+1];
                gg[0]=a0.x; gg[1]=a0.y; gg[2]=a0.z; gg[3]=a0.w;
                gg[4]=a1.x; gg[5]=a1.y; gg[6]=a1.z; gg[7]=a1.w;
                bbv[0]=c0.x; bbv[1]=c0.y; bbv[2]=c0.z; bbv[3]=c0.w;
                bbv[4]=c1.x; bbv[5]=c1.y; bbv[6]=c1.z; bbv[7]=c1.w;
                u16x8 vh, vl;
                #pragma unroll
                for (int e = 0; e < 8; ++e) {
                    float nv = (h[8*u2+e] - mean) * rstd * gg[e] + bbv[e];
                    unsigned short hh = f32_to_bf16_rn(nv);
                    vh[e] = hh;
                    vl[e] = f32_to_bf16_rn(nv - bf16_to_f32(hh));
                }
                unsigned off = ((r * 256u + q * 64u + (unsigned)u2 * 16u) ^ ((r & 7u) << 4));
                *(u16x8*)(lds + AHI_OFF + off) = vh;
                *(u16x8*)(lds + ALO_OFF + off) = vl;
            }
        }
        __syncthreads();

        f32x4 acc2[4][2];
        #pragma unroll
        for (int m = 0; m < 4; ++m) { acc2[m][0] = FZ; acc2[m][1] = FZ; }

        #pragma unroll
        for (int hN = 0; hN < 2; ++hN) {
            // ---- GEMM1 half hN: LN1out[64x128] @ w1[:,hN*128..+128) ----
            f32x4 acc1[4][2];
            #pragma unroll
            for (int m = 0; m < 4; ++m) { acc1[m][0] = FZ; acc1[m][1] = FZ; }
            #pragma unroll
            for (int ks = 0; ks < 4; ++ks) {
                bf16x8 ah[4], al[4];
                #pragma unroll
                for (int m = 0; m < 4; ++m) {
                    unsigned rowA = (unsigned)m * 16u + lr;
                    unsigned off = ((rowA * 256u + (unsigned)ks * 64u + lg * 16u) ^ ((rowA & 7u) << 4));
                    ah[m] = *(const bf16x8*)(lds + AHI_OFF + off);
                    al[m] = *(const bf16x8*)(lds + ALO_OFF + off);
                }
                #pragma unroll
                for (int n = 0; n < 2; ++n) {
                    unsigned ntg = (unsigned)hN * 8u + w * 2u + (unsigned)n;
                    const bf16x8 bh = *(const bf16x8*)(const void*)
                        (w1cv + ((((unsigned)mod * 2u + 0u) * 4u + (unsigned)ks) * 16u + ntg) * 512u + l * 8u);
                    const bf16x8 bl = *(const bf16x8*)(const void*)
                        (w1cv + ((((unsigned)mod * 2u + 1u) * 4u + (unsigned)ks) * 16u + ntg) * 512u + l * 8u);
                    #pragma unroll
                    for (int m = 0; m < 4; ++m) {
                        acc1[m][n] = MFMA16(ah[m], bh, acc1[m][n]);
                        acc1[m][n] = MFMA16(al[m], bh, acc1[m][n]);
                        acc1[m][n] = MFMA16(ah[m], bl, acc1[m][n]);
                    }
                }
            }
            if (hN == 1) __syncthreads();   // all waves done reading H (GEMM2 pass 0)
            // ---- bias1 + exact GELU -> H planes (bf16 hi/lo) ----
            #pragma unroll
            for (int n = 0; n < 2; ++n) {
                unsigned c128 = w * 32u + (unsigned)n * 16u + lr;
                float bb = bias1[(unsigned)mod * 256u + (unsigned)hN * 128u + c128];
                #pragma unroll
                for (int m = 0; m < 4; ++m) {
                    #pragma unroll
                    for (int j = 0; j < 4; ++j) {
                        unsigned rowA = (unsigned)m * 16u + drow + (unsigned)j;
                        float ge = gelu_exact(acc1[m][n][j] + bb);
                        unsigned short hh = f32_to_bf16_rn(ge);
                        unsigned short ll = f32_to_bf16_rn(ge - bf16_to_f32(hh));
                        unsigned off = ((rowA * 256u + c128 * 2u) ^ ((rowA & 7u) << 4));
                        *(unsigned short*)(lds + HHI_OFF + off) = hh;
                        *(unsigned short*)(lds + HLO_OFF + off) = ll;
                    }
                }
            }
            __syncthreads();
            // ---- GEMM2 pass hN: H[64x128] @ w2[hN*128..+128, :] -> acc2 ----
            #pragma unroll
            for (int ks = 0; ks < 4; ++ks) {
                bf16x8 ah[4], al[4];
                #pragma unroll
                for (int m = 0; m < 4; ++m) {
                    unsigned rowA = (unsigned)m * 16u + lr;
                    unsigned off = ((rowA * 256u + (unsigned)ks * 64u + lg * 16u) ^ ((rowA & 7u) << 4));
                    ah[m] = *(const bf16x8*)(lds + HHI_OFF + off);
                    al[m] = *(const bf16x8*)(lds + HLO_OFF + off);
                }
                unsigned kt = (unsigned)hN * 4u + (unsigned)ks;
                #pragma unroll
                for (int n = 0; n < 2; ++n) {
                    unsigned nt2 = w * 2u + (unsigned)n;
                    const bf16x8 bh = *(const bf16x8*)(const void*)
                        (w2cv + ((((unsigned)mod * 2u + 0u) * 8u + kt) * 8u + nt2) * 512u + l * 8u);
                    const bf16x8 bl = *(const bf16x8*)(const void*)
                        (w2cv + ((((unsigned)mod * 2u + 1u) * 8u + kt) * 8u + nt2) * 512u + l * 8u);
                    #pragma unroll
                    for (int m = 0; m < 4; ++m) {
                        acc2[m][n] = MFMA16(ah[m], bh, acc2[m][n]);
                        acc2[m][n] = MFMA16(al[m], bh, acc2[m][n]);
                        acc2[m][n] = MFMA16(ah[m], bl, acc2[m][n]);
                    }
                }
            }
        }
        // ---- acc2 + b2 -> f32 buffer (reuses A region; swizzled) ----
        #pragma unroll
        for (int n = 0; n < 2; ++n) {
            unsigned c = w * 32u + (unsigned)n * 16u + lr;
            float bb = bias2[(unsigned)mod * 128u + c];
            #pragma unroll
            for (int m = 0; m < 4; ++m) {
                #pragma unroll
                for (int j = 0; j < 4; ++j) {
                    unsigned rowA = (unsigned)m * 16u + drow + (unsigned)j;
                    unsigned off = ((rowA * 512u + c * 4u) ^ ((rowA & 7u) << 4));
                    *(float*)(lds + off) = acc2[m][n][j] + bb;
                }
            }
        }
        __syncthreads();
        // ------------- LN2 -> S += state -------------
        {
            float h2[32];
            #pragma unroll
            for (int e = 0; e < 8; ++e) {
                unsigned off = ((r * 512u + (q * 32u + (unsigned)e * 4u) * 4u) ^ ((r & 7u) << 4));
                float4 v = *(const float4*)(lds + off);
                h2[4*e+0] = v.x; h2[4*e+1] = v.y; h2[4*e+2] = v.z; h2[4*e+3] = v.w;
            }
            float s = 0.f, ss = 0.f;
            #pragma unroll
            for (int j = 0; j < 32; ++j) { s += h2[j]; ss += h2[j] * h2[j]; }
            s += __shfl_xor(s, 1); ss += __shfl_xor(ss, 1);
            s += __shfl_xor(s, 2); ss += __shfl_xor(ss, 2);
            const float mean = s * (1.0f / 128.0f);
            const float var  = ss * (1.0f / 128.0f) - mean * mean;
            const float rstd = 1.0f / sqrtf(var + 1e-5f);
            const float4* gp = (const float4*)(ln2_g + (unsigned)mod * 128u + q * 32u);
            const float4* bp = (const float4*)(ln2_b + (unsigned)mod * 128u + q * 32u);
            #pragma unroll
            for (int u = 0; u < 8; ++u) {
                float4 g4 = gp[u], b4 = bp[u];
                Sv[4*u+0] += (h2[4*u+0] - mean) * rstd * g4.x + b4.x;
                Sv[4*u+1] += (h2[4*u+1] - mean) * rstd * g4.y + b4.y;
                Sv[4*u+2] += (h2[4*u+2] - mean) * rstd * g4.z + b4.z;
                Sv[4*u+3] += (h2[4*u+3] - mean) * rstd * g4.w + b4.w;
            }
        }
        __syncthreads();   // A region (== f32 buffer) rewritten by next LN1
    }

    // ------------- final: LN(S/8) -> A planes -------------
    {
        float h[32];
        #pragma unroll
        for (int j = 0; j < 32; ++j) h[j] = Sv[j] * 0.125f;
        float s = 0.f, ss = 0.f;
        #pragma unroll
        for (int j = 0; j < 32; ++j) { s += h[j]; ss += h[j] * h[j]; }
        s += __shfl_xor(s, 1); ss += __shfl_xor(ss, 1);
        s += __shfl_xor(s, 2); ss += __shfl_xor(ss, 2);
        const float mean = s * (1.0f / 128.0f);
        const float var  = ss * (1.0f / 128.0f) - mean * mean;
        const float rstd = 1.0f / sqrtf(var + 1e-5f);
        const float4* gp = (const float4*)(cln_g + q * 32u);
        const float4* bp = (const float4*)(cln_b + q * 32u);
        #pragma unroll
        for (int u2 = 0; u2 < 4; ++u2) {
            float gg[8], bbv[8];
            float4 a0 = gp[2*u2], a1 = gp[2*u2+1];
            float4 c0 = bp[2*u2], c1 = bp[2*u2+1];
            gg[0]=a0.x; gg[1]=a0.y; gg[2]=a0.z; gg[3]=a0.w;
            gg[4]=a1.x; gg[5]=a1.y; gg[6]=a1.z; gg[7]=a1.w;
            bbv[0]=c0.x; bbv[1]=c0.y; bbv[2]=c0.z; bbv[3]=c0.w;
            bbv[4]=c1.x; bbv[5]=c1.y; bbv[6]=c1.z; bbv[7]=c1.w;
            u16x8 vh, vl;
            #pragma unroll
            for (int e = 0; e < 8; ++e) {
                float nv = (h[8*u2+e] - mean) * rstd * gg[e] + bbv[e];
                unsigned short hh = f32_to_bf16_rn(nv);
                vh[e] = hh;
                vl[e] = f32_to_bf16_rn(nv - bf16_to_f32(hh));
            }
            unsigned off = ((r * 256u + q * 64u + (unsigned)u2 * 16u) ^ ((r & 7u) << 4));
            *(u16x8*)(lds + AHI_OFF + off) = vh;
            *(u16x8*)(lds + ALO_OFF + off) = vl;
        }
    }
    __syncthreads();
    // ------------- final GEMM: LN(s) @ comb_w + comb_b -> out -------------
    {
        f32x4 acc3[4][2];
        #pragma unroll
        for (int m = 0; m < 4; ++m) { acc3[m][0] = FZ; acc3[m][1] = FZ; }
        #pragma unroll
        for (int ks = 0; ks < 4; ++ks) {
            bf16x8 ah[4], al[4];
            #pragma unroll
            for (int m = 0; m < 4; ++m) {
                unsigned rowA = (unsigned)m * 16u + lr;
                unsigned off = ((rowA * 256u + (unsigned)ks * 64u + lg * 16u) ^ ((rowA & 7u) << 4));
                ah[m] = *(const bf16x8*)(lds + AHI_OFF + off);
                al[m] = *(const bf16x8*)(lds + ALO_OFF + off);
            }
            #pragma unroll
            for (int n = 0; n < 2; ++n) {
                unsigned nt = w * 2u + (unsigned)n;
                const bf16x8 bh = *(const bf16x8*)(const void*)
                    (cwcv + ((0u * 4u + (unsigned)ks) * 8u + nt) * 512u + l * 8u);
                const bf16x8 bl = *(const bf16x8*)(const void*)
                    (cwcv + ((1u * 4u + (unsigned)ks) * 8u + nt) * 512u + l * 8u);
                #pragma unroll
                for (int m = 0; m < 4; ++m) {
                    acc3[m][n] = MFMA16(ah[m], bh, acc3[m][n]);
                    acc3[m][n] = MFMA16(al[m], bh, acc3[m][n]);
                    acc3[m][n] = MFMA16(ah[m], bl, acc3[m][n]);
                }
            }
        }
        #pragma unroll
        for (int n = 0; n < 2; ++n) {
            unsigned c = w * 32u + (unsigned)n * 16u + lr;
            float bb = comb_b[c];
            #pragma unroll
            for (int m = 0; m < 4; ++m) {
                #pragma unroll
                for (int j = 0; j < 4; ++j) {
                    unsigned rowA = (unsigned)m * 16u + drow + (unsigned)j;
                    out[(row0 + rowA) * 128u + c] = acc3[m][n][j] + bb;
                }
            }
        }
    }
}

extern "C" void kernel_launch(void* const* d_in, const int* in_sizes, int n_in,
                              void* d_out, int out_size, void* d_ws, size_t ws_size,
                              hipStream_t stream)
{
    const float* x    = (const float*)d_in[0];
    const float* fb   = (const float*)d_in[1];
    const float* sm   = (const float*)d_in[2];
    const float* ln1g = (const float*)d_in[3];
    const float* ln1b = (const float*)d_in[4];
    const float* w1   = (const float*)d_in[5];
    const float* b1   = (const float*)d_in[6];
    const float* w2   = (const float*)d_in[7];
    const float* b2   = (const float*)d_in[8];
    const float* ln2g = (const float*)d_in[9];
    const float* ln2b = (const float*)d_in[10];
    const float* clng = (const float*)d_in[11];
    const float* clnb = (const float*)d_in[12];
    const float* cw   = (const float*)d_in[13];
    const float* cb   = (const float*)d_in[14];
    float* out = (float*)d_out;
    char* ws = (char*)d_ws;
    unsigned short* w1cv = (unsigned short*)(ws + WS_W1);
    unsigned short* w2cv = (unsigned short*)(ws + WS_W2);
    unsigned short* cwcv = (unsigned short*)(ws + WS_CW);
    float*          fvp  = (float*)(ws + WS_FV);

    setup_weights<<<dim3(2112), dim3(256), 0, stream>>>(w1, w2, cw, w1cv, w2cv, cwcv);
    setup_fv<<<dim3(4), dim3(256), 0, stream>>>(fb, sm, fvp);
    holo_main<<<dim3(2048), dim3(256), 0, stream>>>(x, ln1g, ln1b, b1, b2, ln2g, ln2b,
                                                    clng, clnb, cb, w1cv, w2cv, cwcv, fvp, out);
    (void)in_sizes; (void)n_in; (void)out_size; (void)ws_size;
}